// Round 1
// baseline (1079.527 us; speedup 1.0000x reference)
//
#include <hip/hip_runtime.h>
#include <hip/hip_bf16.h>

#define D 128
#define TM 64

__device__ __forceinline__ void atomAddF(float* p, float v) {
#ifdef __HIP_PLATFORM_AMD__
    unsafeAtomicAdd(p, v);   // native global_atomic_add_f32 on gfx950
#else
    atomicAdd(p, v);
#endif
}

// copy x -> second half of output; zero degree counters
__global__ void k_init(const float4* __restrict__ x4, float4* __restrict__ out2,
                       int* __restrict__ cnt, int n4, int nnodes) {
    int i = blockIdx.x * blockDim.x + threadIdx.x;
    if (i < n4) out2[i] = x4[i];
    if (i < nnodes) cnt[i] = 0;
}

__global__ void k_count(const int* __restrict__ dst, int* __restrict__ cnt, int ne) {
    int e = blockIdx.x * blockDim.x + threadIdx.x;
    if (e < ne) atomicAdd(&cnt[dst[e]], 1);
}

__global__ void k_dis(const int* __restrict__ cnt, float* __restrict__ dis, int n) {
    int i = blockIdx.x * blockDim.x + threadIdx.x;
    if (i < n) dis[i] = rsqrtf((float)cnt[i] + 1.0f);  // +1 = self loop
}

// H = A @ W ; AGG = dis^2 * H  (self-loop term pre-seeded into accumulator)
__global__ __launch_bounds__(256) void k_gemm(
    const float* __restrict__ A, const float* __restrict__ W,
    const float* __restrict__ dis, float* __restrict__ H,
    float* __restrict__ AGG, int nrows) {
    __shared__ float xs[TM][D];
    __shared__ float ws[D][D];
    const int t = threadIdx.x;
    const int rbase = blockIdx.x * TM;

    for (int i = t; i < D * D / 4; i += 256)
        ((float4*)ws)[i] = ((const float4*)W)[i];
    for (int i = t; i < TM * D / 4; i += 256) {
        int r = i >> 5;           // 32 float4 per row
        int gr = rbase + r;
        float4 v = make_float4(0.f, 0.f, 0.f, 0.f);
        if (gr < nrows) v = ((const float4*)A)[(size_t)gr * 32 + (i & 31)];
        ((float4*)xs)[i] = v;     // zero-fill OOB rows (ws poison safety)
    }
    __syncthreads();

    const int cg = (t & 31) * 4;  // this thread's 4 columns
    const int rs = t >> 5;        // row slot 0..7; rows rs, rs+8, ..., rs+56
    float acc[8][4];
#pragma unroll
    for (int rr = 0; rr < 8; ++rr)
        acc[rr][0] = acc[rr][1] = acc[rr][2] = acc[rr][3] = 0.f;

    for (int k = 0; k < D; k += 4) {
        float4 w0 = *(const float4*)&ws[k + 0][cg];
        float4 w1 = *(const float4*)&ws[k + 1][cg];
        float4 w2 = *(const float4*)&ws[k + 2][cg];
        float4 w3 = *(const float4*)&ws[k + 3][cg];
#pragma unroll
        for (int rr = 0; rr < 8; ++rr) {
            float4 a = *(const float4*)&xs[rs + rr * 8][k];
            acc[rr][0] += a.x * w0.x + a.y * w1.x + a.z * w2.x + a.w * w3.x;
            acc[rr][1] += a.x * w0.y + a.y * w1.y + a.z * w2.y + a.w * w3.y;
            acc[rr][2] += a.x * w0.z + a.y * w1.z + a.z * w2.z + a.w * w3.z;
            acc[rr][3] += a.x * w0.w + a.y * w1.w + a.z * w2.w + a.w * w3.w;
        }
    }

#pragma unroll
    for (int rr = 0; rr < 8; ++rr) {
        int gr = rbase + rs + rr * 8;
        if (gr < nrows) {
            float dv = dis[gr];
            float d2 = dv * dv;
            float4 hv = make_float4(acc[rr][0], acc[rr][1], acc[rr][2], acc[rr][3]);
            ((float4*)H)[(size_t)gr * 32 + (cg >> 2)] = hv;
            float4 av = make_float4(d2 * hv.x, d2 * hv.y, d2 * hv.z, d2 * hv.w);
            ((float4*)AGG)[(size_t)gr * 32 + (cg >> 2)] = av;
        }
    }
}

// one wave per edge: AGG[dst] += dis[src]*dis[dst] * H[src]
__global__ void k_scatter(const int* __restrict__ ei, const float* __restrict__ dis,
                          const float* __restrict__ H, float* __restrict__ AGG, int ne) {
    int gid = blockIdx.x * blockDim.x + threadIdx.x;
    int e = gid >> 6;
    int lane = gid & 63;
    if (e >= ne) return;
    int src = ei[e];
    int dst = ei[ne + e];
    float norm = dis[src] * dis[dst];
    float2 v = *(const float2*)&H[(size_t)src * D + lane * 2];
    float* p = &AGG[(size_t)dst * D + lane * 2];
    atomAddF(p, norm * v.x);
    atomAddF(p + 1, norm * v.y);
}

// out = tanh(AGG + b)
__global__ void k_epi(const float4* __restrict__ AGG4, const float* __restrict__ b,
                      float4* __restrict__ out4, int n4) {
    int i = blockIdx.x * blockDim.x + threadIdx.x;
    if (i >= n4) return;
    float4 a = AGG4[i];
    float4 bb = ((const float4*)b)[i & 31];
    out4[i] = make_float4(tanhf(a.x + bb.x), tanhf(a.y + bb.y),
                          tanhf(a.z + bb.z), tanhf(a.w + bb.w));
}

extern "C" void kernel_launch(void* const* d_in, const int* in_sizes, int n_in,
                              void* d_out, int out_size, void* d_ws, size_t ws_size,
                              hipStream_t stream) {
    const float* x  = (const float*)d_in[0];
    const int*   ei = (const int*)d_in[1];   // [2, E] int32: src then dst
    const float* W1 = (const float*)d_in[2];
    const float* b1 = (const float*)d_in[3];
    const float* W2 = (const float*)d_in[4];
    const float* b2 = (const float*)d_in[5];
    const int N = in_sizes[0] / D;   // 50000
    const int E = in_sizes[1] / 2;   // 500000
    float* out = (float*)d_out;

    char* ws = (char*)d_ws;
    int*   cnt = (int*)ws;                                    // 200KB
    float* dis = (float*)(ws + (1u << 20));                   // 200KB
    float* H   = (float*)(ws + (2u << 20));                   // 25.6MB
    float* AGG = (float*)(ws + (size_t)28 * (1u << 20));      // 25.6MB
    float* H1  = (float*)(ws + (size_t)54 * (1u << 20));      // 25.6MB

    const int n4 = N * D / 4;                 // 1.6M float4
    const int nb = (n4 + 255) / 256;
    const int gblocks = (N + TM - 1) / TM;
    const int sblocks = (E * 64 + 255) / 256;

    k_init<<<nb, 256, 0, stream>>>((const float4*)x, (float4*)(out + (size_t)N * D), cnt, n4, N);
    k_count<<<(E + 255) / 256, 256, 0, stream>>>(ei + E, cnt, E);
    k_dis<<<(N + 255) / 256, 256, 0, stream>>>(cnt, dis, N);

    // layer 1
    k_gemm<<<gblocks, 256, 0, stream>>>(x, W1, dis, H, AGG, N);
    k_scatter<<<sblocks, 256, 0, stream>>>(ei, dis, H, AGG, E);
    k_epi<<<nb, 256, 0, stream>>>((const float4*)AGG, b1, (float4*)H1, n4);

    // layer 2
    k_gemm<<<gblocks, 256, 0, stream>>>(H1, W2, dis, H, AGG, N);
    k_scatter<<<sblocks, 256, 0, stream>>>(ei, dis, H, AGG, E);
    k_epi<<<nb, 256, 0, stream>>>((const float4*)AGG, b2, (float4*)out, n4);
}

// Round 2
// 435.386 us; speedup vs baseline: 2.4795x; 2.4795x over previous
//
#include <hip/hip_runtime.h>
#include <hip/hip_bf16.h>

#define D 128
#define TM 64
#define SCAN_T 1024

// copy x -> second half of output; zero degree counters + cursors
__global__ void k_init(const float4* __restrict__ x4, float4* __restrict__ out2,
                       int* __restrict__ cnt, int* __restrict__ cur, int n4, int nnodes) {
    int i = blockIdx.x * blockDim.x + threadIdx.x;
    if (i < n4) out2[i] = x4[i];
    if (i < nnodes) { cnt[i] = 0; cur[i] = 0; }
}

__global__ void k_count(const int* __restrict__ dst, int* __restrict__ cnt, int ne) {
    int e = blockIdx.x * blockDim.x + threadIdx.x;
    if (e < ne) atomicAdd(&cnt[dst[e]], 1);
}

__global__ void k_dis(const int* __restrict__ cnt, float* __restrict__ dis, int n) {
    int i = blockIdx.x * blockDim.x + threadIdx.x;
    if (i < n) dis[i] = rsqrtf((float)cnt[i] + 1.0f);  // +1 = self loop
}

// single-workgroup exclusive scan: rowptr[0..n], rowptr[n] = total
__global__ __launch_bounds__(SCAN_T) void k_scan(const int* __restrict__ cnt,
                                                 int* __restrict__ rowptr, int n) {
    __shared__ int part[SCAN_T];
    const int t = threadIdx.x;
    const int chunk = (n + SCAN_T - 1) / SCAN_T;
    const int lo = t * chunk;
    const int hi = min(lo + chunk, n);
    int s = 0;
    for (int i = lo; i < hi; ++i) s += cnt[i];
    part[t] = s;
    __syncthreads();
    for (int off = 1; off < SCAN_T; off <<= 1) {
        int add = (t >= off) ? part[t - off] : 0;
        __syncthreads();
        part[t] += add;
        __syncthreads();
    }
    int run = part[t] - s;  // exclusive prefix
    for (int i = lo; i < hi; ++i) { rowptr[i] = run; run += cnt[i]; }
    if (hi == n && lo <= n) rowptr[n] = run;
}

__global__ void k_fill(const int* __restrict__ ei, const int* __restrict__ rowptr,
                       int* __restrict__ cur, int* __restrict__ adj, int ne) {
    int e = blockIdx.x * blockDim.x + threadIdx.x;
    if (e >= ne) return;
    int s = ei[e];
    int d = ei[ne + e];
    int p = rowptr[d] + atomicAdd(&cur[d], 1);
    adj[p] = s;
}

// H = A @ W  (plain GEMM, 64-row tile, W + x-tile in LDS)
__global__ __launch_bounds__(256) void k_gemm(
    const float* __restrict__ A, const float* __restrict__ W,
    float* __restrict__ H, int nrows) {
    __shared__ float xs[TM][D];
    __shared__ float ws[D][D];
    const int t = threadIdx.x;
    const int rbase = blockIdx.x * TM;

    for (int i = t; i < D * D / 4; i += 256)
        ((float4*)ws)[i] = ((const float4*)W)[i];
    for (int i = t; i < TM * D / 4; i += 256) {
        int r = i >> 5;
        int gr = rbase + r;
        float4 v = make_float4(0.f, 0.f, 0.f, 0.f);
        if (gr < nrows) v = ((const float4*)A)[(size_t)gr * 32 + (i & 31)];
        ((float4*)xs)[i] = v;
    }
    __syncthreads();

    const int cg = (t & 31) * 4;
    const int rs = t >> 5;
    float acc[8][4];
#pragma unroll
    for (int rr = 0; rr < 8; ++rr)
        acc[rr][0] = acc[rr][1] = acc[rr][2] = acc[rr][3] = 0.f;

    for (int k = 0; k < D; k += 4) {
        float4 w0 = *(const float4*)&ws[k + 0][cg];
        float4 w1 = *(const float4*)&ws[k + 1][cg];
        float4 w2 = *(const float4*)&ws[k + 2][cg];
        float4 w3 = *(const float4*)&ws[k + 3][cg];
#pragma unroll
        for (int rr = 0; rr < 8; ++rr) {
            float4 a = *(const float4*)&xs[rs + rr * 8][k];
            acc[rr][0] += a.x * w0.x + a.y * w1.x + a.z * w2.x + a.w * w3.x;
            acc[rr][1] += a.x * w0.y + a.y * w1.y + a.z * w2.y + a.w * w3.y;
            acc[rr][2] += a.x * w0.z + a.y * w1.z + a.z * w2.z + a.w * w3.z;
            acc[rr][3] += a.x * w0.w + a.y * w1.w + a.z * w2.w + a.w * w3.w;
        }
    }

#pragma unroll
    for (int rr = 0; rr < 8; ++rr) {
        int gr = rbase + rs + rr * 8;
        if (gr < nrows)
            ((float4*)H)[(size_t)gr * 32 + (cg >> 2)] =
                make_float4(acc[rr][0], acc[rr][1], acc[rr][2], acc[rr][3]);
    }
}

// one wave per node: out[i] = tanh( sum_{s->i} dis[s]*dis[i]*H[s] + dis[i]^2*H[i] + b )
__global__ __launch_bounds__(256) void k_gather(
    const int* __restrict__ rowptr, const int* __restrict__ adj,
    const float* __restrict__ dis, const float* __restrict__ H,
    const float* __restrict__ b, float* __restrict__ out, int n) {
    int node = blockIdx.x * 4 + (threadIdx.x >> 6);
    if (node >= n) return;
    int lane = threadIdx.x & 63;
    int beg = rowptr[node];
    int end = rowptr[node + 1];
    float di = dis[node];

    float2 hv = *(const float2*)&H[(size_t)node * D + lane * 2];
    float2 acc = make_float2(di * di * hv.x, di * di * hv.y);

    int e = beg;
    for (; e + 1 < end; e += 2) {
        int s0 = adj[e];
        int s1 = adj[e + 1];
        float n0 = dis[s0] * di;
        float n1 = dis[s1] * di;
        float2 v0 = *(const float2*)&H[(size_t)s0 * D + lane * 2];
        float2 v1 = *(const float2*)&H[(size_t)s1 * D + lane * 2];
        acc.x += n0 * v0.x + n1 * v1.x;
        acc.y += n0 * v0.y + n1 * v1.y;
    }
    if (e < end) {
        int s0 = adj[e];
        float n0 = dis[s0] * di;
        float2 v0 = *(const float2*)&H[(size_t)s0 * D + lane * 2];
        acc.x += n0 * v0.x;
        acc.y += n0 * v0.y;
    }

    float2 bb = *(const float2*)&b[lane * 2];
    float2 r = make_float2(tanhf(acc.x + bb.x), tanhf(acc.y + bb.y));
    *(float2*)&out[(size_t)node * D + lane * 2] = r;
}

extern "C" void kernel_launch(void* const* d_in, const int* in_sizes, int n_in,
                              void* d_out, int out_size, void* d_ws, size_t ws_size,
                              hipStream_t stream) {
    const float* x  = (const float*)d_in[0];
    const int*   ei = (const int*)d_in[1];   // [2, E] int32: src then dst
    const float* W1 = (const float*)d_in[2];
    const float* b1 = (const float*)d_in[3];
    const float* W2 = (const float*)d_in[4];
    const float* b2 = (const float*)d_in[5];
    const int N = in_sizes[0] / D;   // 50000
    const int E = in_sizes[1] / 2;   // 500000
    float* out = (float*)d_out;

    char* ws = (char*)d_ws;
    int*   cnt    = (int*)ws;                                  // 200KB
    int*   cur    = (int*)(ws + (1u << 20));                   // 200KB
    float* dis    = (float*)(ws + (2u << 20));                 // 200KB
    int*   rowptr = (int*)(ws + (3u << 20));                   // 200KB+4
    int*   adj    = (int*)(ws + (4u << 20));                   // 2MB
    float* H      = (float*)(ws + (8u << 20));                 // 25.6MB
    float* H1     = (float*)(ws + (size_t)36 * (1u << 20));    // 25.6MB

    const int n4 = N * D / 4;
    const int nb = (n4 + 255) / 256;
    const int gblocks = (N + TM - 1) / TM;
    const int ablocks = (N + 3) / 4;   // 4 nodes (waves) per block

    k_init<<<nb, 256, 0, stream>>>((const float4*)x, (float4*)(out + (size_t)N * D),
                                   cnt, cur, n4, N);
    k_count<<<(E + 255) / 256, 256, 0, stream>>>(ei + E, cnt, E);
    k_scan<<<1, SCAN_T, 0, stream>>>(cnt, rowptr, N);
    k_dis<<<(N + 255) / 256, 256, 0, stream>>>(cnt, dis, N);
    k_fill<<<(E + 255) / 256, 256, 0, stream>>>(ei, rowptr, cur, adj, E);

    // layer 1
    k_gemm<<<gblocks, 256, 0, stream>>>(x, W1, H, N);
    k_gather<<<ablocks, 256, 0, stream>>>(rowptr, adj, dis, H, b1, H1, N);

    // layer 2
    k_gemm<<<gblocks, 256, 0, stream>>>(H1, W2, H, N);
    k_gather<<<ablocks, 256, 0, stream>>>(rowptr, adj, dis, H, b2, out, N);
}

// Round 3
// 330.653 us; speedup vs baseline: 3.2648x; 1.3167x over previous
//
#include <hip/hip_runtime.h>
#include <hip/hip_bf16.h>

#define D 128
#define TM 64
#define PADE (1 << 20)   // max padded CSR entries (E + N + pad <= 700K < 1M)

__device__ __forceinline__ float bflo(unsigned u) { return __uint_as_float(u << 16); }
__device__ __forceinline__ float bfhi(unsigned u) { return __uint_as_float(u & 0xffff0000u); }
__device__ __forceinline__ unsigned f2bf(float f) {
    unsigned u = __float_as_uint(f);
    return (u + 0x7fffu + ((u >> 16) & 1u)) >> 16;   // RNE
}

// copy x -> second half of output; zero cnt; zero padded adj/wnorm
__global__ void k_init(const float4* __restrict__ x4, float4* __restrict__ out2,
                       int* __restrict__ cnt, int* __restrict__ adj,
                       float* __restrict__ wnorm, int n4, int nnodes) {
    int i = blockIdx.x * blockDim.x + threadIdx.x;
    if (i < n4) out2[i] = x4[i];
    if (i < nnodes) cnt[i] = 0;
    if (i < PADE) { adj[i] = 0; wnorm[i] = 0.f; }
}

__global__ void k_count(const int* __restrict__ dst, int* __restrict__ cnt, int ne) {
    int e = blockIdx.x * blockDim.x + threadIdx.x;
    if (e < ne) atomicAdd(&cnt[dst[e]], 1);
}

// phase 1: per-block (256 nodes) sum of padded degrees
__global__ __launch_bounds__(256) void k_scan1(const int* __restrict__ cnt,
                                               int* __restrict__ partials, int n) {
    int i = blockIdx.x * 256 + threadIdx.x;
    int v = (i < n) ? ((cnt[i] + 4) & ~3) : 0;   // deg + self, round up to 4
#pragma unroll
    for (int off = 32; off >= 1; off >>= 1) v += __shfl_down(v, off, 64);
    __shared__ int red[4];
    int wid = threadIdx.x >> 6, lane = threadIdx.x & 63;
    if (lane == 0) red[wid] = v;
    __syncthreads();
    if (threadIdx.x == 0) partials[blockIdx.x] = red[0] + red[1] + red[2] + red[3];
}

// phase 2: single block, exclusive scan of <=256 partials (in place)
__global__ __launch_bounds__(256) void k_scan2(int* __restrict__ partials, int nb) {
    __shared__ int s[256];
    int t = threadIdx.x;
    int v = (t < nb) ? partials[t] : 0;
    s[t] = v;
    __syncthreads();
    for (int off = 1; off < 256; off <<= 1) {
        int a = (t >= off) ? s[t - off] : 0;
        __syncthreads();
        s[t] += a;
        __syncthreads();
    }
    partials[t] = s[t] - v;   // exclusive
}

// phase 3: per-block local scan + base; write rowptr, dis, self-edge, cursor
__global__ __launch_bounds__(256) void k_scan3(
    const int* __restrict__ cnt, const int* __restrict__ partials,
    int* __restrict__ rowptr, float* __restrict__ dis, int* __restrict__ cur,
    int* __restrict__ adj, float* __restrict__ wnorm, int n) {
    __shared__ int s[256];
    int t = threadIdx.x;
    int i = blockIdx.x * 256 + t;
    int deg = (i < n) ? cnt[i] : 0;
    int pdeg = (i < n) ? ((deg + 4) & ~3) : 0;
    s[t] = pdeg;
    __syncthreads();
    for (int off = 1; off < 256; off <<= 1) {
        int a = (t >= off) ? s[t - off] : 0;
        __syncthreads();
        s[t] += a;
        __syncthreads();
    }
    if (i < n) {
        int rp = partials[blockIdx.x] + s[t] - pdeg;
        rowptr[i] = rp;
        float di = rsqrtf((float)deg + 1.0f);
        dis[i] = di;
        adj[rp] = i;            // self loop as edge 0
        wnorm[rp] = di * di;
        cur[i] = 1;             // fill appends after the self loop
        if (i == n - 1) rowptr[n] = rp + pdeg;
    }
}

__global__ void k_fill(const int* __restrict__ ei, const int* __restrict__ rowptr,
                       const float* __restrict__ dis, int* __restrict__ cur,
                       int* __restrict__ adj, float* __restrict__ wnorm, int ne) {
    int e = blockIdx.x * blockDim.x + threadIdx.x;
    if (e >= ne) return;
    int s = ei[e];
    int d = ei[ne + e];
    int p = rowptr[d] + atomicAdd(&cur[d], 1);
    adj[p] = s;
    wnorm[p] = dis[s] * dis[d];
}

// H(bf16) = A(f32) @ W(f32); f32 accumulate, RNE pack on store
__global__ __launch_bounds__(256) void k_gemm(
    const float* __restrict__ A, const float* __restrict__ W,
    unsigned* __restrict__ Hb, int nrows) {
    __shared__ float xs[TM][D];
    __shared__ float ws[D][D];
    const int t = threadIdx.x;
    const int rbase = blockIdx.x * TM;

    for (int i = t; i < D * D / 4; i += 256)
        ((float4*)ws)[i] = ((const float4*)W)[i];
    for (int i = t; i < TM * D / 4; i += 256) {
        int r = i >> 5;
        int gr = rbase + r;
        float4 v = make_float4(0.f, 0.f, 0.f, 0.f);
        if (gr < nrows) v = ((const float4*)A)[(size_t)gr * 32 + (i & 31)];
        ((float4*)xs)[i] = v;
    }
    __syncthreads();

    const int cg = (t & 31) * 4;
    const int rs = t >> 5;
    float acc[8][4];
#pragma unroll
    for (int rr = 0; rr < 8; ++rr)
        acc[rr][0] = acc[rr][1] = acc[rr][2] = acc[rr][3] = 0.f;

    for (int k = 0; k < D; k += 4) {
        float4 w0 = *(const float4*)&ws[k + 0][cg];
        float4 w1 = *(const float4*)&ws[k + 1][cg];
        float4 w2 = *(const float4*)&ws[k + 2][cg];
        float4 w3 = *(const float4*)&ws[k + 3][cg];
#pragma unroll
        for (int rr = 0; rr < 8; ++rr) {
            float4 a = *(const float4*)&xs[rs + rr * 8][k];
            acc[rr][0] += a.x * w0.x + a.y * w1.x + a.z * w2.x + a.w * w3.x;
            acc[rr][1] += a.x * w0.y + a.y * w1.y + a.z * w2.y + a.w * w3.y;
            acc[rr][2] += a.x * w0.z + a.y * w1.z + a.z * w2.z + a.w * w3.z;
            acc[rr][3] += a.x * w0.w + a.y * w1.w + a.z * w2.w + a.w * w3.w;
        }
    }

#pragma unroll
    for (int rr = 0; rr < 8; ++rr) {
        int gr = rbase + rs + rr * 8;
        if (gr < nrows) {
            uint2 p;
            p.x = f2bf(acc[rr][0]) | (f2bf(acc[rr][1]) << 16);
            p.y = f2bf(acc[rr][2]) | (f2bf(acc[rr][3]) << 16);
            ((uint2*)Hb)[(size_t)gr * 32 + (cg >> 2)] = p;
        }
    }
}

// one wave per node; padded CSR (self loop included, pads have w=0)
__global__ __launch_bounds__(256) void k_gather(
    const int* __restrict__ rowptr, const int* __restrict__ adj,
    const float* __restrict__ wnorm, const unsigned* __restrict__ Hb,
    const float* __restrict__ b, float* __restrict__ out, int n) {
    int node = blockIdx.x * 4 + (threadIdx.x >> 6);
    if (node >= n) return;
    int lane = threadIdx.x & 63;
    int beg = rowptr[node];
    int end = rowptr[node + 1];

    float ax = 0.f, ay = 0.f;
    for (int e = beg; e < end; e += 4) {
        int4 ss = *(const int4*)(adj + e);
        float4 ww = *(const float4*)(wnorm + e);
        unsigned u0 = Hb[(size_t)ss.x * 64 + lane];
        unsigned u1 = Hb[(size_t)ss.y * 64 + lane];
        unsigned u2 = Hb[(size_t)ss.z * 64 + lane];
        unsigned u3 = Hb[(size_t)ss.w * 64 + lane];
        ax += ww.x * bflo(u0) + ww.y * bflo(u1) + ww.z * bflo(u2) + ww.w * bflo(u3);
        ay += ww.x * bfhi(u0) + ww.y * bfhi(u1) + ww.z * bfhi(u2) + ww.w * bfhi(u3);
    }

    float2 bb = *(const float2*)&b[lane * 2];
    float2 r = make_float2(tanhf(ax + bb.x), tanhf(ay + bb.y));
    *(float2*)&out[(size_t)node * D + lane * 2] = r;
}

extern "C" void kernel_launch(void* const* d_in, const int* in_sizes, int n_in,
                              void* d_out, int out_size, void* d_ws, size_t ws_size,
                              hipStream_t stream) {
    const float* x  = (const float*)d_in[0];
    const int*   ei = (const int*)d_in[1];   // [2, E] int32: src then dst
    const float* W1 = (const float*)d_in[2];
    const float* b1 = (const float*)d_in[3];
    const float* W2 = (const float*)d_in[4];
    const float* b2 = (const float*)d_in[5];
    const int N = in_sizes[0] / D;   // 50000
    const int E = in_sizes[1] / 2;   // 500000
    float* out = (float*)d_out;

    char* ws = (char*)d_ws;
    const size_t MB = 1u << 20;
    int*      cnt      = (int*)ws;                    // 200KB
    int*      partials = (int*)(ws + 1 * MB);         // 1KB
    int*      cur      = (int*)(ws + 2 * MB);         // 200KB
    float*    dis      = (float*)(ws + 3 * MB);       // 200KB
    int*      rowptr   = (int*)(ws + 4 * MB);         // 200KB+4
    int*      adj      = (int*)(ws + 5 * MB);         // 4MB
    float*    wnorm    = (float*)(ws + 9 * MB);       // 4MB
    unsigned* Hb       = (unsigned*)(ws + 13 * MB);   // 12.8MB (bf16)
    float*    H1       = (float*)(ws + 26 * MB);      // 25.6MB

    const int n4 = N * D / 4;
    const int nb = (n4 + 255) / 256;                  // also covers PADE zeroing
    const int sb = (N + 255) / 256;                   // scan blocks (196)
    const int gblocks = (N + TM - 1) / TM;
    const int ablocks = (N + 3) / 4;

    k_init<<<nb, 256, 0, stream>>>((const float4*)x, (float4*)(out + (size_t)N * D),
                                   cnt, adj, wnorm, n4, N);
    k_count<<<(E + 255) / 256, 256, 0, stream>>>(ei + E, cnt, E);
    k_scan1<<<sb, 256, 0, stream>>>(cnt, partials, N);
    k_scan2<<<1, 256, 0, stream>>>(partials, sb);
    k_scan3<<<sb, 256, 0, stream>>>(cnt, partials, rowptr, dis, cur, adj, wnorm, N);
    k_fill<<<(E + 255) / 256, 256, 0, stream>>>(ei, rowptr, dis, cur, adj, wnorm, E);

    // layer 1
    k_gemm<<<gblocks, 256, 0, stream>>>(x, W1, Hb, N);
    k_gather<<<ablocks, 256, 0, stream>>>(rowptr, adj, wnorm, Hb, b1, H1, N);

    // layer 2
    k_gemm<<<gblocks, 256, 0, stream>>>(H1, W2, Hb, N);
    k_gather<<<ablocks, 256, 0, stream>>>(rowptr, adj, wnorm, Hb, b2, out, N);
}

// Round 4
// 259.575 us; speedup vs baseline: 4.1588x; 1.2738x over previous
//
#include <hip/hip_runtime.h>
#include <hip/hip_bf16.h>

#define D 128
#define PADE (1 << 20)   // padded CSR entries capacity (<= 700K used)

typedef short bf16x8 __attribute__((ext_vector_type(8)));
typedef float f32x4  __attribute__((ext_vector_type(4)));

__device__ __forceinline__ float bflo(unsigned u) { return __uint_as_float(u << 16); }
__device__ __forceinline__ float bfhi(unsigned u) { return __uint_as_float(u & 0xffff0000u); }
__device__ __forceinline__ unsigned f2bf(float f) {
    unsigned u = __float_as_uint(f);
    return (u + 0x7fffu + ((u >> 16) & 1u)) >> 16;   // RNE
}

// copy x -> second half of output; pack x -> bf16 Xb; zero cnt + padded adj/wnorm
__global__ void k_init(const float4* __restrict__ x4, float4* __restrict__ out2,
                       uint2* __restrict__ Xb2, int* __restrict__ cnt,
                       int* __restrict__ adj, float* __restrict__ wnorm,
                       int n4, int nnodes) {
    int i = blockIdx.x * blockDim.x + threadIdx.x;
    if (i < n4) {
        float4 v = x4[i];
        out2[i] = v;
        uint2 p;
        p.x = f2bf(v.x) | (f2bf(v.y) << 16);
        p.y = f2bf(v.z) | (f2bf(v.w) << 16);
        Xb2[i] = p;
    }
    if (i < nnodes) cnt[i] = 0;
    if (i < PADE) { adj[i] = 0; wnorm[i] = 0.f; }
}

__global__ void k_count(const int* __restrict__ dst, int* __restrict__ cnt, int ne) {
    int e = blockIdx.x * blockDim.x + threadIdx.x;
    if (e < ne) atomicAdd(&cnt[dst[e]], 1);
}

// W1,W2 (f32 [k][n]) -> Wt1,Wt2 (bf16 [n][k])
__global__ __launch_bounds__(256) void k_prew(const float* __restrict__ W1,
                                              const float* __restrict__ W2,
                                              ushort* __restrict__ Wt1,
                                              ushort* __restrict__ Wt2) {
    int i = blockIdx.x * 256 + threadIdx.x;        // 0..32767
    const float* W = (i < 16384) ? W1 : W2;
    ushort* Wt = (i < 16384) ? Wt1 : Wt2;
    int j = i & 16383;
    int n = j >> 7, k = j & 127;
    Wt[n * 128 + k] = (ushort)f2bf(W[k * 128 + n]);
}

// phase 1: per-block (256 nodes) sum of padded degrees
__global__ __launch_bounds__(256) void k_scan1(const int* __restrict__ cnt,
                                               int* __restrict__ partials, int n) {
    int i = blockIdx.x * 256 + threadIdx.x;
    int v = (i < n) ? ((cnt[i] + 4) & ~3) : 0;   // deg + self, round up to 4
#pragma unroll
    for (int off = 32; off >= 1; off >>= 1) v += __shfl_down(v, off, 64);
    __shared__ int red[4];
    int wid = threadIdx.x >> 6, lane = threadIdx.x & 63;
    if (lane == 0) red[wid] = v;
    __syncthreads();
    if (threadIdx.x == 0) partials[blockIdx.x] = red[0] + red[1] + red[2] + red[3];
}

// phase 2: single block, exclusive scan of <=256 partials (in place)
__global__ __launch_bounds__(256) void k_scan2(int* __restrict__ partials, int nb) {
    __shared__ int s[256];
    int t = threadIdx.x;
    int v = (t < nb) ? partials[t] : 0;
    s[t] = v;
    __syncthreads();
    for (int off = 1; off < 256; off <<= 1) {
        int a = (t >= off) ? s[t - off] : 0;
        __syncthreads();
        s[t] += a;
        __syncthreads();
    }
    partials[t] = s[t] - v;
}

// phase 3: per-block local scan + base; write rowptr, dis, self-edge, cursor
__global__ __launch_bounds__(256) void k_scan3(
    const int* __restrict__ cnt, const int* __restrict__ partials,
    int* __restrict__ rowptr, float* __restrict__ dis, int* __restrict__ cur,
    int* __restrict__ adj, float* __restrict__ wnorm, int n) {
    __shared__ int s[256];
    int t = threadIdx.x;
    int i = blockIdx.x * 256 + t;
    int deg = (i < n) ? cnt[i] : 0;
    int pdeg = (i < n) ? ((deg + 4) & ~3) : 0;
    s[t] = pdeg;
    __syncthreads();
    for (int off = 1; off < 256; off <<= 1) {
        int a = (t >= off) ? s[t - off] : 0;
        __syncthreads();
        s[t] += a;
        __syncthreads();
    }
    if (i < n) {
        int rp = partials[blockIdx.x] + s[t] - pdeg;
        rowptr[i] = rp;
        float di = rsqrtf((float)deg + 1.0f);
        dis[i] = di;
        adj[rp] = i;            // self loop as edge 0
        wnorm[rp] = di * di;
        cur[i] = 1;
        if (i == n - 1) rowptr[n] = rp + pdeg;
    }
}

__global__ void k_fill(const int* __restrict__ ei, const int* __restrict__ rowptr,
                       const float* __restrict__ dis, int* __restrict__ cur,
                       int* __restrict__ adj, float* __restrict__ wnorm, int ne) {
    int e = blockIdx.x * blockDim.x + threadIdx.x;
    if (e >= ne) return;
    int s = ei[e];
    int d = ei[ne + e];
    int p = rowptr[d] + atomicAdd(&cur[d], 1);
    adj[p] = s;
    wnorm[p] = dis[s] * dis[d];
}

// Hb(bf16) = Ab(bf16) @ Wt^T via MFMA 16x16x32. One wave per 16-row strip,
// 8 col-tiles x 4 k-chunks = 32 MFMA. No LDS in main loop (Wt is L1-resident).
__global__ __launch_bounds__(256) void k_gemm_mfma(
    const ushort* __restrict__ Ab, const ushort* __restrict__ Wt,
    uint* __restrict__ Hb, int nstrips) {
    __shared__ ushort lds[4][16][136];   // [wave][row][col] pad->16B-aligned rows
    const int wid = threadIdx.x >> 6;
    const int lane = threadIdx.x & 63;
    const int strip = blockIdx.x * 4 + wid;
    if (strip >= nstrips) return;
    const int m = lane & 15, quad = lane >> 4;

    f32x4 acc[8];
#pragma unroll
    for (int t = 0; t < 8; ++t) acc[t] = (f32x4){0.f, 0.f, 0.f, 0.f};

    const ushort* arow = Ab + ((size_t)strip * 16 + m) * 128 + quad * 8;
    const ushort* wrow = Wt + (size_t)m * 128 + quad * 8;
#pragma unroll
    for (int kc = 0; kc < 4; ++kc) {
        bf16x8 a = *(const bf16x8*)(arow + kc * 32);
#pragma unroll
        for (int t = 0; t < 8; ++t) {
            bf16x8 b = *(const bf16x8*)(wrow + t * 16 * 128 + kc * 32);
            acc[t] = __builtin_amdgcn_mfma_f32_16x16x32_bf16(a, b, acc[t], 0, 0, 0);
        }
    }

    // C/D layout: col = t*16 + (lane&15), row = quad*4 + reg  ->  row-major bf16
#pragma unroll
    for (int t = 0; t < 8; ++t)
#pragma unroll
        for (int r = 0; r < 4; ++r)
            lds[wid][quad * 4 + r][t * 16 + m] = (ushort)f2bf(acc[t][r]);
    // same-wave LDS readback (compiler inserts lgkmcnt wait); coalesced store
    const int lr = lane >> 2, seg = lane & 3;
    uint4* dst = (uint4*)(Hb + ((size_t)strip * 16 + lr) * 64 + seg * 16);
    const ushort* src = &lds[wid][lr][seg * 32];
#pragma unroll
    for (int j = 0; j < 4; ++j) dst[j] = *(const uint4*)(src + j * 8);
}

// one wave per node; padded CSR (self loop included, pads have w=0)
template <bool BF16OUT>
__global__ __launch_bounds__(256) void k_gather(
    const int* __restrict__ rowptr, const int* __restrict__ adj,
    const float* __restrict__ wnorm, const unsigned* __restrict__ Hb,
    const float* __restrict__ b, void* __restrict__ out, int n) {
    int node = blockIdx.x * 4 + (threadIdx.x >> 6);
    if (node >= n) return;
    int lane = threadIdx.x & 63;
    int beg = rowptr[node];
    int end = rowptr[node + 1];

    float ax = 0.f, ay = 0.f;
    for (int e = beg; e < end; e += 4) {
        int4 ss = *(const int4*)(adj + e);
        float4 ww = *(const float4*)(wnorm + e);
        unsigned u0 = Hb[(size_t)ss.x * 64 + lane];
        unsigned u1 = Hb[(size_t)ss.y * 64 + lane];
        unsigned u2 = Hb[(size_t)ss.z * 64 + lane];
        unsigned u3 = Hb[(size_t)ss.w * 64 + lane];
        ax += ww.x * bflo(u0) + ww.y * bflo(u1) + ww.z * bflo(u2) + ww.w * bflo(u3);
        ay += ww.x * bfhi(u0) + ww.y * bfhi(u1) + ww.z * bfhi(u2) + ww.w * bfhi(u3);
    }

    float2 bb = *(const float2*)&b[lane * 2];
    float rx = tanhf(ax + bb.x), ry = tanhf(ay + bb.y);
    if (BF16OUT) {
        ((unsigned*)out)[(size_t)node * 64 + lane] = f2bf(rx) | (f2bf(ry) << 16);
    } else {
        *(float2*)&((float*)out)[(size_t)node * D + lane * 2] = make_float2(rx, ry);
    }
}

extern "C" void kernel_launch(void* const* d_in, const int* in_sizes, int n_in,
                              void* d_out, int out_size, void* d_ws, size_t ws_size,
                              hipStream_t stream) {
    const float* x  = (const float*)d_in[0];
    const int*   ei = (const int*)d_in[1];   // [2, E] int32: src then dst
    const float* W1 = (const float*)d_in[2];
    const float* b1 = (const float*)d_in[3];
    const float* W2 = (const float*)d_in[4];
    const float* b2 = (const float*)d_in[5];
    const int N = in_sizes[0] / D;   // 50000
    const int E = in_sizes[1] / 2;   // 500000
    float* out = (float*)d_out;

    char* ws = (char*)d_ws;
    const size_t KB = 1024, MB = 1024 * KB;
    int*    cnt      = (int*)(ws + 0);             // 200KB
    int*    cur      = (int*)(ws + 256 * KB);      // 200KB
    float*  dis      = (float*)(ws + 512 * KB);    // 200KB
    int*    rowptr   = (int*)(ws + 768 * KB);      // 200KB+4
    int*    partials = (int*)(ws + 1000 * KB);     // 1KB
    int*    adj      = (int*)(ws + 1 * MB);        // 4MB
    float*  wnorm    = (float*)(ws + 5 * MB);      // 4MB
    ushort* Xb       = (ushort*)(ws + 9 * MB);     // 12.3MiB
    uint*   Hb       = (uint*)(ws + 22 * MB);      // 12.3MiB
    uint*   H1b      = (uint*)(ws + 35 * MB);      // 12.3MiB
    ushort* Wt1      = (ushort*)(ws + 48 * MB);    // 32KB
    ushort* Wt2      = (ushort*)(ws + 48 * MB + 64 * KB);

    const int n4 = N * D / 4;
    const int nb = (n4 + 255) / 256;              // covers PADE zeroing too
    const int sb = (N + 255) / 256;
    const int nstrips = (N + 15) / 16;            // 3125
    const int mblocks = (nstrips + 3) / 4;
    const int ablocks = (N + 3) / 4;

    k_init<<<nb, 256, 0, stream>>>((const float4*)x, (float4*)(out + (size_t)N * D),
                                   (uint2*)Xb, cnt, adj, wnorm, n4, N);
    k_count<<<(E + 255) / 256, 256, 0, stream>>>(ei + E, cnt, E);
    k_prew<<<128, 256, 0, stream>>>(W1, W2, Wt1, Wt2);
    k_scan1<<<sb, 256, 0, stream>>>(cnt, partials, N);
    k_scan2<<<1, 256, 0, stream>>>(partials, sb);
    k_scan3<<<sb, 256, 0, stream>>>(cnt, partials, rowptr, dis, cur, adj, wnorm, N);
    k_fill<<<(E + 255) / 256, 256, 0, stream>>>(ei, rowptr, dis, cur, adj, wnorm, E);

    // layer 1
    k_gemm_mfma<<<mblocks, 256, 0, stream>>>(Xb, Wt1, Hb, nstrips);
    k_gather<true><<<ablocks, 256, 0, stream>>>(rowptr, adj, wnorm, Hb, b1, (void*)H1b, N);

    // layer 2
    k_gemm_mfma<<<mblocks, 256, 0, stream>>>((const ushort*)H1b, Wt2, Hb, nstrips);
    k_gather<false><<<ablocks, 256, 0, stream>>>(rowptr, adj, wnorm, Hb, b2, (void*)out, N);
}

// Round 5
// 248.618 us; speedup vs baseline: 4.3421x; 1.0441x over previous
//
#include <hip/hip_runtime.h>
#include <hip/hip_bf16.h>

#define D 128

typedef short bf16x8 __attribute__((ext_vector_type(8)));
typedef float f32x4  __attribute__((ext_vector_type(4)));

__device__ __forceinline__ float bflo(unsigned u) { return __uint_as_float(u << 16); }
__device__ __forceinline__ float bfhi(unsigned u) { return __uint_as_float(u & 0xffff0000u); }
__device__ __forceinline__ unsigned f2bf(float f) {
    unsigned u = __float_as_uint(f);
    return (u + 0x7fffu + ((u >> 16) & 1u)) >> 16;   // RNE
}

// merged pre-pass, range-split by blockIdx:
//   [0, nb)          : copy x -> out2 ; pack x -> bf16 Xb
//   [nb, nb+128)     : W1,W2 (f32 [k][n]) -> Wt1,Wt2 (bf16 [n][k])
//   [nb+128, +cb)    : degree count atomics (cnt pre-zeroed by memset)
__global__ __launch_bounds__(256) void k_pre(
    const float4* __restrict__ x4, float4* __restrict__ out2, uint2* __restrict__ Xb2,
    const float* __restrict__ W1, const float* __restrict__ W2,
    ushort* __restrict__ Wt1, ushort* __restrict__ Wt2,
    const int* __restrict__ dst, int* __restrict__ cnt,
    int n4, int ne, int nb) {
    const int blk = blockIdx.x, t = threadIdx.x;
    if (blk < nb) {
        int i = blk * 256 + t;
        if (i < n4) {
            float4 v = x4[i];
            out2[i] = v;
            uint2 p;
            p.x = f2bf(v.x) | (f2bf(v.y) << 16);
            p.y = f2bf(v.z) | (f2bf(v.w) << 16);
            Xb2[i] = p;
        }
    } else if (blk < nb + 128) {
        int i = (blk - nb) * 256 + t;          // 0..32767
        const float* W = (i < 16384) ? W1 : W2;
        ushort* Wt = (i < 16384) ? Wt1 : Wt2;
        int j = i & 16383;
        int n = j >> 7, k = j & 127;
        Wt[n * 128 + k] = (ushort)f2bf(W[k * 128 + n]);
    } else {
        int e = (blk - nb - 128) * 256 + t;
        if (e < ne) atomicAdd(&cnt[dst[e]], 1);
    }
}

// phase 1: per-block (256 nodes) sum of padded degrees
__global__ __launch_bounds__(256) void k_scan1(const int* __restrict__ cnt,
                                               int* __restrict__ partials, int n) {
    int i = blockIdx.x * 256 + threadIdx.x;
    int v = (i < n) ? ((cnt[i] + 4) & ~3) : 0;   // deg + self, round up to 4
#pragma unroll
    for (int off = 32; off >= 1; off >>= 1) v += __shfl_down(v, off, 64);
    __shared__ int red[4];
    int wid = threadIdx.x >> 6, lane = threadIdx.x & 63;
    if (lane == 0) red[wid] = v;
    __syncthreads();
    if (threadIdx.x == 0) partials[blockIdx.x] = red[0] + red[1] + red[2] + red[3];
}

// phase 2+3 merged: every block redundantly scans the <=256 partials in LDS,
// then local node scan; writes rowptr, dis, self-edge, pads, cursor
__global__ __launch_bounds__(256) void k_scan3(
    const int* __restrict__ cnt, const int* __restrict__ partials,
    int* __restrict__ rowptr, float* __restrict__ dis, int* __restrict__ cur,
    int* __restrict__ adj, float* __restrict__ wnorm, int n, int nblk) {
    __shared__ int sp[256];
    __shared__ int s[256];
    const int t = threadIdx.x;
    // inclusive scan of block partials (redundant per block; ~free)
    int pv = (t < nblk) ? partials[t] : 0;
    sp[t] = pv;
    __syncthreads();
    for (int off = 1; off < 256; off <<= 1) {
        int a = (t >= off) ? sp[t - off] : 0;
        __syncthreads();
        sp[t] += a;
        __syncthreads();
    }
    // local scan of padded degrees
    int i = blockIdx.x * 256 + t;
    int deg = (i < n) ? cnt[i] : 0;
    int pdeg = (i < n) ? ((deg + 4) & ~3) : 0;
    s[t] = pdeg;
    __syncthreads();
    for (int off = 1; off < 256; off <<= 1) {
        int a = (t >= off) ? s[t - off] : 0;
        __syncthreads();
        s[t] += a;
        __syncthreads();
    }
    int base = sp[blockIdx.x] - partials[blockIdx.x];   // exclusive block prefix
    if (i < n) {
        int rp = base + s[t] - pdeg;
        rowptr[i] = rp;
        float di = rsqrtf((float)deg + 1.0f);
        dis[i] = di;
        adj[rp] = i;            // self loop as edge 0
        wnorm[rp] = di * di;
        cur[i] = 1;             // fill appends after the self loop
        for (int p = deg + 1; p < pdeg; ++p) {   // <=3 pad slots
            adj[rp + p] = 0;
            wnorm[rp + p] = 0.f;
        }
        if (i == n - 1) rowptr[n] = rp + pdeg;
    }
}

__global__ void k_fill(const int* __restrict__ ei, const int* __restrict__ rowptr,
                       const float* __restrict__ dis, int* __restrict__ cur,
                       int* __restrict__ adj, float* __restrict__ wnorm, int ne) {
    int e = blockIdx.x * blockDim.x + threadIdx.x;
    if (e >= ne) return;
    int s = ei[e];
    int d = ei[ne + e];
    int p = rowptr[d] + atomicAdd(&cur[d], 1);
    adj[p] = s;
    wnorm[p] = dis[s] * dis[d];
}

// Hb(bf16) = Ab(bf16) @ Wt^T via MFMA 16x16x32. One wave per 16-row strip,
// 8 col-tiles x 4 k-chunks = 32 MFMA. No LDS in main loop (Wt is L1-resident).
__global__ __launch_bounds__(256) void k_gemm_mfma(
    const ushort* __restrict__ Ab, const ushort* __restrict__ Wt,
    uint* __restrict__ Hb, int nstrips) {
    __shared__ ushort lds[4][16][136];
    const int wid = threadIdx.x >> 6;
    const int lane = threadIdx.x & 63;
    const int strip = blockIdx.x * 4 + wid;
    if (strip >= nstrips) return;
    const int m = lane & 15, quad = lane >> 4;

    f32x4 acc[8];
#pragma unroll
    for (int t = 0; t < 8; ++t) acc[t] = (f32x4){0.f, 0.f, 0.f, 0.f};

    const ushort* arow = Ab + ((size_t)strip * 16 + m) * 128 + quad * 8;
    const ushort* wrow = Wt + (size_t)m * 128 + quad * 8;
#pragma unroll
    for (int kc = 0; kc < 4; ++kc) {
        bf16x8 a = *(const bf16x8*)(arow + kc * 32);
#pragma unroll
        for (int t = 0; t < 8; ++t) {
            bf16x8 b = *(const bf16x8*)(wrow + t * 16 * 128 + kc * 32);
            acc[t] = __builtin_amdgcn_mfma_f32_16x16x32_bf16(a, b, acc[t], 0, 0, 0);
        }
    }

    // C/D layout: col = t*16 + (lane&15), row = quad*4 + reg  ->  row-major bf16
#pragma unroll
    for (int t = 0; t < 8; ++t)
#pragma unroll
        for (int r = 0; r < 4; ++r)
            lds[wid][quad * 4 + r][t * 16 + m] = (ushort)f2bf(acc[t][r]);
    const int lr = lane >> 2, seg = lane & 3;
    uint4* dst = (uint4*)(Hb + ((size_t)strip * 16 + lr) * 64 + seg * 16);
    const ushort* src = &lds[wid][lr][seg * 32];
#pragma unroll
    for (int j = 0; j < 4; ++j) dst[j] = *(const uint4*)(src + j * 8);
}

// one wave per node; padded CSR (self loop included, pads -> node 0 with w=0).
// Edge loop unrolled x8: 8 independent 256B row-loads in flight.
template <bool BF16OUT>
__global__ __launch_bounds__(256) void k_gather(
    const int* __restrict__ rowptr, const int* __restrict__ adj,
    const float* __restrict__ wnorm, const unsigned* __restrict__ Hb,
    const float* __restrict__ b, void* __restrict__ out, int n) {
    int node = blockIdx.x * 4 + (threadIdx.x >> 6);
    if (node >= n) return;
    int lane = threadIdx.x & 63;
    int beg = rowptr[node];
    int end = rowptr[node + 1];

    float ax = 0.f, ay = 0.f;
    int e = beg;
    for (; e + 8 <= end; e += 8) {
        int4 sa = *(const int4*)(adj + e);
        int4 sb = *(const int4*)(adj + e + 4);
        float4 wa = *(const float4*)(wnorm + e);
        float4 wb = *(const float4*)(wnorm + e + 4);
        unsigned u0 = Hb[(size_t)sa.x * 64 + lane];
        unsigned u1 = Hb[(size_t)sa.y * 64 + lane];
        unsigned u2 = Hb[(size_t)sa.z * 64 + lane];
        unsigned u3 = Hb[(size_t)sa.w * 64 + lane];
        unsigned u4 = Hb[(size_t)sb.x * 64 + lane];
        unsigned u5 = Hb[(size_t)sb.y * 64 + lane];
        unsigned u6 = Hb[(size_t)sb.z * 64 + lane];
        unsigned u7 = Hb[(size_t)sb.w * 64 + lane];
        ax += wa.x * bflo(u0) + wa.y * bflo(u1) + wa.z * bflo(u2) + wa.w * bflo(u3)
            + wb.x * bflo(u4) + wb.y * bflo(u5) + wb.z * bflo(u6) + wb.w * bflo(u7);
        ay += wa.x * bfhi(u0) + wa.y * bfhi(u1) + wa.z * bfhi(u2) + wa.w * bfhi(u3)
            + wb.x * bfhi(u4) + wb.y * bfhi(u5) + wb.z * bfhi(u6) + wb.w * bfhi(u7);
    }
    if (e < end) {   // pad=4 => remainder is exactly 0 or 4
        int4 sa = *(const int4*)(adj + e);
        float4 wa = *(const float4*)(wnorm + e);
        unsigned u0 = Hb[(size_t)sa.x * 64 + lane];
        unsigned u1 = Hb[(size_t)sa.y * 64 + lane];
        unsigned u2 = Hb[(size_t)sa.z * 64 + lane];
        unsigned u3 = Hb[(size_t)sa.w * 64 + lane];
        ax += wa.x * bflo(u0) + wa.y * bflo(u1) + wa.z * bflo(u2) + wa.w * bflo(u3);
        ay += wa.x * bfhi(u0) + wa.y * bfhi(u1) + wa.z * bfhi(u2) + wa.w * bfhi(u3);
    }

    float2 bb = *(const float2*)&b[lane * 2];
    float rx = tanhf(ax + bb.x), ry = tanhf(ay + bb.y);
    if (BF16OUT) {
        ((unsigned*)out)[(size_t)node * 64 + lane] = f2bf(rx) | (f2bf(ry) << 16);
    } else {
        *(float2*)&((float*)out)[(size_t)node * D + lane * 2] = make_float2(rx, ry);
    }
}

extern "C" void kernel_launch(void* const* d_in, const int* in_sizes, int n_in,
                              void* d_out, int out_size, void* d_ws, size_t ws_size,
                              hipStream_t stream) {
    const float* x  = (const float*)d_in[0];
    const int*   ei = (const int*)d_in[1];   // [2, E] int32: src then dst
    const float* W1 = (const float*)d_in[2];
    const float* b1 = (const float*)d_in[3];
    const float* W2 = (const float*)d_in[4];
    const float* b2 = (const float*)d_in[5];
    const int N = in_sizes[0] / D;   // 50000
    const int E = in_sizes[1] / 2;   // 500000
    float* out = (float*)d_out;

    char* ws = (char*)d_ws;
    const size_t KB = 1024, MB = 1024 * KB;
    int*    cnt      = (int*)(ws + 0);             // 200KB
    int*    cur      = (int*)(ws + 256 * KB);      // 200KB
    float*  dis      = (float*)(ws + 512 * KB);    // 200KB
    int*    rowptr   = (int*)(ws + 768 * KB);      // 200KB+4
    int*    partials = (int*)(ws + 1000 * KB);     // 1KB
    int*    adj      = (int*)(ws + 1 * MB);        // 4MB
    float*  wnorm    = (float*)(ws + 5 * MB);      // 4MB
    ushort* Xb       = (ushort*)(ws + 9 * MB);     // 12.3MiB
    uint*   Hb       = (uint*)(ws + 22 * MB);      // 12.3MiB
    uint*   H1b      = (uint*)(ws + 35 * MB);      // 12.3MiB
    ushort* Wt1      = (ushort*)(ws + 48 * MB);    // 32KB
    ushort* Wt2      = (ushort*)(ws + 48 * MB + 64 * KB);

    const int n4 = N * D / 4;
    const int nb = (n4 + 255) / 256;              // 6250
    const int cb = (E + 255) / 256;               // 1954
    const int sb = (N + 255) / 256;               // 196
    const int nstrips = (N + 15) / 16;            // 3125
    const int mblocks = (nstrips + 3) / 4;
    const int ablocks = (N + 3) / 4;

    hipMemsetAsync(cnt, 0, (size_t)N * sizeof(int), stream);
    k_pre<<<nb + 128 + cb, 256, 0, stream>>>(
        (const float4*)x, (float4*)(out + (size_t)N * D), (uint2*)Xb,
        W1, W2, Wt1, Wt2, ei + E, cnt, n4, E, nb);
    k_scan1<<<sb, 256, 0, stream>>>(cnt, partials, N);
    k_scan3<<<sb, 256, 0, stream>>>(cnt, partials, rowptr, dis, cur, adj, wnorm, N, sb);
    k_fill<<<cb, 256, 0, stream>>>(ei, rowptr, dis, cur, adj, wnorm, E);

    // layer 1
    k_gemm_mfma<<<mblocks, 256, 0, stream>>>(Xb, Wt1, Hb, nstrips);
    k_gather<true><<<ablocks, 256, 0, stream>>>(rowptr, adj, wnorm, Hb, b1, (void*)H1b, N);

    // layer 2
    k_gemm_mfma<<<mblocks, 256, 0, stream>>>((const ushort*)H1b, Wt2, Hb, nstrips);
    k_gather<false><<<ablocks, 256, 0, stream>>>(rowptr, adj, wnorm, Hb, b2, (void*)out, N);
}

// Round 6
// 220.893 us; speedup vs baseline: 4.8871x; 1.1255x over previous
//
#include <hip/hip_runtime.h>
#include <hip/hip_bf16.h>

#define D 128

typedef short bf16x8 __attribute__((ext_vector_type(8)));
typedef float f32x4  __attribute__((ext_vector_type(4)));

__device__ __forceinline__ float bflo(unsigned u) { return __uint_as_float(u << 16); }
__device__ __forceinline__ float bfhi(unsigned u) { return __uint_as_float(u & 0xffff0000u); }
__device__ __forceinline__ unsigned f2bf(float f) {
    unsigned u = __float_as_uint(f);
    return (u + 0x7fffu + ((u >> 16) & 1u)) >> 16;   // RNE
}

// merged pre-pass, range-split by blockIdx:
//   [0, nb)          : copy x -> out2 ; pack x -> bf16 Xb
//   [nb, nb+128)     : W1,W2 (f32 [k][n]) -> Wt1,Wt2 (bf16 [n][k])
//   [nb+128, +cb)    : degree count atomics (cnt pre-zeroed by memset)
__global__ __launch_bounds__(256) void k_pre(
    const float4* __restrict__ x4, float4* __restrict__ out2, uint2* __restrict__ Xb2,
    const float* __restrict__ W1, const float* __restrict__ W2,
    ushort* __restrict__ Wt1, ushort* __restrict__ Wt2,
    const int* __restrict__ dst, int* __restrict__ cnt,
    int n4, int ne, int nb) {
    const int blk = blockIdx.x, t = threadIdx.x;
    if (blk < nb) {
        int i = blk * 256 + t;
        if (i < n4) {
            float4 v = x4[i];
            out2[i] = v;
            uint2 p;
            p.x = f2bf(v.x) | (f2bf(v.y) << 16);
            p.y = f2bf(v.z) | (f2bf(v.w) << 16);
            Xb2[i] = p;
        }
    } else if (blk < nb + 128) {
        int i = (blk - nb) * 256 + t;          // 0..32767
        const float* W = (i < 16384) ? W1 : W2;
        ushort* Wt = (i < 16384) ? Wt1 : Wt2;
        int j = i & 16383;
        int n = j >> 7, k = j & 127;
        Wt[n * 128 + k] = (ushort)f2bf(W[k * 128 + n]);
    } else {
        int e = (blk - nb - 128) * 256 + t;
        if (e < ne) atomicAdd(&cnt[dst[e]], 1);
    }
}

// phase 1: per-block (256 nodes) sum of padded degrees
__global__ __launch_bounds__(256) void k_scan1(const int* __restrict__ cnt,
                                               int* __restrict__ partials, int n) {
    int i = blockIdx.x * 256 + threadIdx.x;
    int v = (i < n) ? ((cnt[i] + 4) & ~3) : 0;   // deg + self, round up to 4
#pragma unroll
    for (int off = 32; off >= 1; off >>= 1) v += __shfl_down(v, off, 64);
    __shared__ int red[4];
    int wid = threadIdx.x >> 6, lane = threadIdx.x & 63;
    if (lane == 0) red[wid] = v;
    __syncthreads();
    if (threadIdx.x == 0) partials[blockIdx.x] = red[0] + red[1] + red[2] + red[3];
}

// phase 2+3 merged: every block redundantly scans the <=256 partials in LDS,
// then local node scan; writes rowptr, dis, self-edge pair, pads, cursor
__global__ __launch_bounds__(256) void k_scan3(
    const int* __restrict__ cnt, const int* __restrict__ partials,
    int* __restrict__ rowptr, float* __restrict__ dis, int* __restrict__ cur,
    int2* __restrict__ ew, int n, int nblk) {
    __shared__ int sp[256];
    __shared__ int s[256];
    const int t = threadIdx.x;
    int pv = (t < nblk) ? partials[t] : 0;
    sp[t] = pv;
    __syncthreads();
    for (int off = 1; off < 256; off <<= 1) {
        int a = (t >= off) ? sp[t - off] : 0;
        __syncthreads();
        sp[t] += a;
        __syncthreads();
    }
    int i = blockIdx.x * 256 + t;
    int deg = (i < n) ? cnt[i] : 0;
    int pdeg = (i < n) ? ((deg + 4) & ~3) : 0;
    s[t] = pdeg;
    __syncthreads();
    for (int off = 1; off < 256; off <<= 1) {
        int a = (t >= off) ? s[t - off] : 0;
        __syncthreads();
        s[t] += a;
        __syncthreads();
    }
    int base = sp[blockIdx.x] - partials[blockIdx.x];   // exclusive block prefix
    if (i < n) {
        int rp = base + s[t] - pdeg;
        rowptr[i] = rp;
        float di = rsqrtf((float)deg + 1.0f);
        dis[i] = di;
        ew[rp] = make_int2(i, __float_as_int(di * di));   // self loop
        cur[i] = 1;
        for (int p = deg + 1; p < pdeg; ++p)              // <=3 pad slots
            ew[rp + p] = make_int2(0, 0);
        if (i == n - 1) rowptr[n] = rp + pdeg;
    }
}

__global__ void k_fill(const int* __restrict__ ei, const int* __restrict__ rowptr,
                       const float* __restrict__ dis, int* __restrict__ cur,
                       int2* __restrict__ ew, int ne) {
    int e = blockIdx.x * blockDim.x + threadIdx.x;
    if (e >= ne) return;
    int s = ei[e];
    int d = ei[ne + e];
    int p = rowptr[d] + atomicAdd(&cur[d], 1);
    ew[p] = make_int2(s, __float_as_int(dis[s] * dis[d]));
}

// Fused layer: per 16-node block, aggregate bf16 input rows (A·X) into an LDS
// tile, then (A·X)·W via MFMA + bias + tanh, coalesced store.
// Ain: packed bf16 rows [N][64] uints. Wt: bf16 [n][k]. 4 waves, 4 nodes/wave.
template <bool BF16OUT>
__global__ __launch_bounds__(256) void k_layer(
    const int* __restrict__ rowptr, const int2* __restrict__ ew,
    const uint* __restrict__ Ain, const ushort* __restrict__ Wt,
    const float* __restrict__ bias, void* __restrict__ out, int n) {
    __shared__ ushort atile[16 * 136];   // row stride 136 (=17*8, 16B-aligned rows)
    __shared__ float otile[16 * 132];
    const int wid = threadIdx.x >> 6;
    const int lane = threadIdx.x & 63;
    const int base = blockIdx.x * 16;
    const int4* ew4 = (const int4*)ew;

    // ---- gather phase: 4 nodes per wave ----
#pragma unroll
    for (int j = 0; j < 4; ++j) {
        int node = base + wid * 4 + j;
        float ax = 0.f, ay = 0.f;
        if (node < n) {
            int beg = rowptr[node];
            int end = rowptr[node + 1];
            int e = beg;
            for (; e + 8 <= end; e += 8) {
                int4 p0 = ew4[(e >> 1) + 0];
                int4 p1 = ew4[(e >> 1) + 1];
                int4 p2 = ew4[(e >> 1) + 2];
                int4 p3 = ew4[(e >> 1) + 3];
                uint u0 = Ain[(size_t)p0.x * 64 + lane];
                uint u1 = Ain[(size_t)p0.z * 64 + lane];
                uint u2 = Ain[(size_t)p1.x * 64 + lane];
                uint u3 = Ain[(size_t)p1.z * 64 + lane];
                uint u4 = Ain[(size_t)p2.x * 64 + lane];
                uint u5 = Ain[(size_t)p2.z * 64 + lane];
                uint u6 = Ain[(size_t)p3.x * 64 + lane];
                uint u7 = Ain[(size_t)p3.z * 64 + lane];
                float w0 = __int_as_float(p0.y), w1 = __int_as_float(p0.w);
                float w2 = __int_as_float(p1.y), w3 = __int_as_float(p1.w);
                float w4 = __int_as_float(p2.y), w5 = __int_as_float(p2.w);
                float w6 = __int_as_float(p3.y), w7 = __int_as_float(p3.w);
                ax += w0 * bflo(u0) + w1 * bflo(u1) + w2 * bflo(u2) + w3 * bflo(u3)
                    + w4 * bflo(u4) + w5 * bflo(u5) + w6 * bflo(u6) + w7 * bflo(u7);
                ay += w0 * bfhi(u0) + w1 * bfhi(u1) + w2 * bfhi(u2) + w3 * bfhi(u3)
                    + w4 * bfhi(u4) + w5 * bfhi(u5) + w6 * bfhi(u6) + w7 * bfhi(u7);
            }
            if (e < end) {   // pad=4 => remainder exactly 0 or 4
                int4 p0 = ew4[(e >> 1) + 0];
                int4 p1 = ew4[(e >> 1) + 1];
                uint u0 = Ain[(size_t)p0.x * 64 + lane];
                uint u1 = Ain[(size_t)p0.z * 64 + lane];
                uint u2 = Ain[(size_t)p1.x * 64 + lane];
                uint u3 = Ain[(size_t)p1.z * 64 + lane];
                float w0 = __int_as_float(p0.y), w1 = __int_as_float(p0.w);
                float w2 = __int_as_float(p1.y), w3 = __int_as_float(p1.w);
                ax += w0 * bflo(u0) + w1 * bflo(u1) + w2 * bflo(u2) + w3 * bflo(u3);
                ay += w0 * bfhi(u0) + w1 * bfhi(u1) + w2 * bfhi(u2) + w3 * bfhi(u3);
            }
        }
        ((uint*)atile)[(wid * 4 + j) * 68 + lane] = f2bf(ax) | (f2bf(ay) << 16);
    }
    __syncthreads();

    // ---- MFMA phase: wave wid computes col tiles {2*wid, 2*wid+1} ----
    const int m = lane & 15, quad = lane >> 4;
    const ushort* arow = atile + m * 136 + quad * 8;
    bf16x8 afr[4];
#pragma unroll
    for (int kc = 0; kc < 4; ++kc) afr[kc] = *(const bf16x8*)(arow + kc * 32);

    f32x4 acc[2];
#pragma unroll
    for (int t2 = 0; t2 < 2; ++t2) {
        acc[t2] = (f32x4){0.f, 0.f, 0.f, 0.f};
        const int t = wid * 2 + t2;
        const ushort* wrow = Wt + (size_t)(t * 16 + m) * 128 + quad * 8;
#pragma unroll
        for (int kc = 0; kc < 4; ++kc) {
            bf16x8 b = *(const bf16x8*)(wrow + kc * 32);
            acc[t2] = __builtin_amdgcn_mfma_f32_16x16x32_bf16(afr[kc], b, acc[t2], 0, 0, 0);
        }
    }

    // ---- epilogue: bias + tanh -> otile (C/D: row=quad*4+r, col=t*16+m) ----
#pragma unroll
    for (int t2 = 0; t2 < 2; ++t2) {
        const int t = wid * 2 + t2;
        float bb = bias[t * 16 + m];
#pragma unroll
        for (int r = 0; r < 4; ++r)
            otile[(quad * 4 + r) * 132 + t * 16 + m] = tanhf(acc[t2][r] + bb);
    }
    __syncthreads();

    // ---- coalesced store: thread -> (row = tid>>4, seg = tid&15) ----
    const int row = threadIdx.x >> 4, seg = threadIdx.x & 15;
    if (base + row < n) {
        const float* src = &otile[row * 132 + seg * 8];
        if (BF16OUT) {
            uint4 p;
            p.x = f2bf(src[0]) | (f2bf(src[1]) << 16);
            p.y = f2bf(src[2]) | (f2bf(src[3]) << 16);
            p.z = f2bf(src[4]) | (f2bf(src[5]) << 16);
            p.w = f2bf(src[6]) | (f2bf(src[7]) << 16);
            ((uint4*)out)[(size_t)(base + row) * 16 + seg] = p;
        } else {
            float4* dst = (float4*)((float*)out + (size_t)(base + row) * 128 + seg * 8);
            dst[0] = *(const float4*)(src);
            dst[1] = *(const float4*)(src + 4);
        }
    }
}

extern "C" void kernel_launch(void* const* d_in, const int* in_sizes, int n_in,
                              void* d_out, int out_size, void* d_ws, size_t ws_size,
                              hipStream_t stream) {
    const float* x  = (const float*)d_in[0];
    const int*   ei = (const int*)d_in[1];   // [2, E] int32: src then dst
    const float* W1 = (const float*)d_in[2];
    const float* b1 = (const float*)d_in[3];
    const float* W2 = (const float*)d_in[4];
    const float* b2 = (const float*)d_in[5];
    const int N = in_sizes[0] / D;   // 50000
    const int E = in_sizes[1] / 2;   // 500000
    float* out = (float*)d_out;

    char* ws = (char*)d_ws;
    const size_t KB = 1024, MB = 1024 * KB;
    int*    cnt      = (int*)(ws + 0);             // 200KB
    int*    cur      = (int*)(ws + 256 * KB);      // 200KB
    float*  dis      = (float*)(ws + 512 * KB);    // 200KB
    int*    rowptr   = (int*)(ws + 768 * KB);      // 200KB+4
    int*    partials = (int*)(ws + 1000 * KB);     // 1KB
    int2*   ew       = (int2*)(ws + 1 * MB);       // 8MB (700K slots max)
    ushort* Xb       = (ushort*)(ws + 9 * MB);     // 12.3MiB
    uint*   H1b      = (uint*)(ws + 22 * MB);      // 12.3MiB
    ushort* Wt1      = (ushort*)(ws + 35 * MB);    // 32KB
    ushort* Wt2      = (ushort*)(ws + 35 * MB + 64 * KB);

    const int n4 = N * D / 4;
    const int nb = (n4 + 255) / 256;              // 6250
    const int cb = (E + 255) / 256;               // 1954
    const int sb = (N + 255) / 256;               // 196
    const int lblocks = (N + 15) / 16;            // 3125

    hipMemsetAsync(cnt, 0, (size_t)N * sizeof(int), stream);
    k_pre<<<nb + 128 + cb, 256, 0, stream>>>(
        (const float4*)x, (float4*)(out + (size_t)N * D), (uint2*)Xb,
        W1, W2, Wt1, Wt2, ei + E, cnt, n4, E, nb);
    k_scan1<<<sb, 256, 0, stream>>>(cnt, partials, N);
    k_scan3<<<sb, 256, 0, stream>>>(cnt, partials, rowptr, dis, cur, ew, N, sb);
    k_fill<<<cb, 256, 0, stream>>>(ei, rowptr, dis, cur, ew, E);

    k_layer<true><<<lblocks, 256, 0, stream>>>(rowptr, ew, (const uint*)Xb, Wt1,
                                               b1, (void*)H1b, N);
    k_layer<false><<<lblocks, 256, 0, stream>>>(rowptr, ew, H1b, Wt2,
                                                b2, (void*)out, N);
}

// Round 7
// 215.001 us; speedup vs baseline: 5.0210x; 1.0274x over previous
//
#include <hip/hip_runtime.h>
#include <hip/hip_bf16.h>

#define D 128

typedef short bf16x8 __attribute__((ext_vector_type(8)));
typedef float f32x4  __attribute__((ext_vector_type(4)));
typedef float f32x2  __attribute__((ext_vector_type(2)));

__device__ __forceinline__ unsigned f2bf(float f) {
    unsigned u = __float_as_uint(f);
    return (u + 0x7fffu + ((u >> 16) & 1u)) >> 16;   // RNE
}

// merged pre-pass, range-split by blockIdx:
//   [0, nb)          : copy x -> out2 ; pack x -> fp8 Xf8
//   [nb, nb+128)     : W1,W2 (f32 [k][n]) -> Wt1,Wt2 (bf16 [n][k])
//   [nb+128, +cb)    : degree count atomics (cnt pre-zeroed by memset)
__global__ __launch_bounds__(256) void k_pre(
    const float4* __restrict__ x4, float4* __restrict__ out2, uint* __restrict__ Xf8,
    const float* __restrict__ W1, const float* __restrict__ W2,
    ushort* __restrict__ Wt1, ushort* __restrict__ Wt2,
    const int* __restrict__ dst, int* __restrict__ cnt,
    int n4, int ne, int nb) {
    const int blk = blockIdx.x, t = threadIdx.x;
    if (blk < nb) {
        int i = blk * 256 + t;
        if (i < n4) {
            float4 v = x4[i];
            out2[i] = v;
            uint q = __builtin_amdgcn_cvt_pk_fp8_f32(v.x, v.y, 0, false);
            q = __builtin_amdgcn_cvt_pk_fp8_f32(v.z, v.w, q, true);
            Xf8[i] = q;   // 4 fp8 bytes per float4 -> row = 32 uints = 128B
        }
    } else if (blk < nb + 128) {
        int i = (blk - nb) * 256 + t;          // 0..32767
        const float* W = (i < 16384) ? W1 : W2;
        ushort* Wt = (i < 16384) ? Wt1 : Wt2;
        int j = i & 16383;
        int n = j >> 7, k = j & 127;
        Wt[n * 128 + k] = (ushort)f2bf(W[k * 128 + n]);
    } else {
        int e = (blk - nb - 128) * 256 + t;
        if (e < ne) atomicAdd(&cnt[dst[e]], 1);
    }
}

// phase 1: per-block (256 nodes) sum of padded degrees
__global__ __launch_bounds__(256) void k_scan1(const int* __restrict__ cnt,
                                               int* __restrict__ partials, int n) {
    int i = blockIdx.x * 256 + threadIdx.x;
    int v = (i < n) ? ((cnt[i] + 4) & ~3) : 0;   // deg + self, round up to 4
#pragma unroll
    for (int off = 32; off >= 1; off >>= 1) v += __shfl_down(v, off, 64);
    __shared__ int red[4];
    int wid = threadIdx.x >> 6, lane = threadIdx.x & 63;
    if (lane == 0) red[wid] = v;
    __syncthreads();
    if (threadIdx.x == 0) partials[blockIdx.x] = red[0] + red[1] + red[2] + red[3];
}

// phase 2+3 merged: every block redundantly scans the <=256 partials in LDS,
// then local node scan; writes rowptr, dis, self-edge pair, pads, cursor
__global__ __launch_bounds__(256) void k_scan3(
    const int* __restrict__ cnt, const int* __restrict__ partials,
    int* __restrict__ rowptr, float* __restrict__ dis, int* __restrict__ cur,
    int2* __restrict__ ew, int n, int nblk) {
    __shared__ int sp[256];
    __shared__ int s[256];
    const int t = threadIdx.x;
    int pv = (t < nblk) ? partials[t] : 0;
    sp[t] = pv;
    __syncthreads();
    for (int off = 1; off < 256; off <<= 1) {
        int a = (t >= off) ? sp[t - off] : 0;
        __syncthreads();
        sp[t] += a;
        __syncthreads();
    }
    int i = blockIdx.x * 256 + t;
    int deg = (i < n) ? cnt[i] : 0;
    int pdeg = (i < n) ? ((deg + 4) & ~3) : 0;
    s[t] = pdeg;
    __syncthreads();
    for (int off = 1; off < 256; off <<= 1) {
        int a = (t >= off) ? s[t - off] : 0;
        __syncthreads();
        s[t] += a;
        __syncthreads();
    }
    int base = sp[blockIdx.x] - partials[blockIdx.x];   // exclusive block prefix
    if (i < n) {
        int rp = base + s[t] - pdeg;
        rowptr[i] = rp;
        float di = rsqrtf((float)deg + 1.0f);
        dis[i] = di;
        ew[rp] = make_int2(i, __float_as_int(di * di));   // self loop
        cur[i] = 1;
        for (int p = deg + 1; p < pdeg; ++p)              // <=3 pad slots
            ew[rp + p] = make_int2(0, 0);
        if (i == n - 1) rowptr[n] = rp + pdeg;
    }
}

__global__ void k_fill(const int* __restrict__ ei, const int* __restrict__ rowptr,
                       const float* __restrict__ dis, int* __restrict__ cur,
                       int2* __restrict__ ew, int ne) {
    int e = blockIdx.x * blockDim.x + threadIdx.x;
    if (e >= ne) return;
    int s = ei[e];
    int d = ei[ne + e];
    int p = rowptr[d] + atomicAdd(&cur[d], 1);
    ew[p] = make_int2(s, __float_as_int(dis[s] * dis[d]));
}

// Fused layer: per 16-node block, aggregate fp8 input rows (A·X) -> f32 ->
// bf16 LDS tile, then (A·X)·W via MFMA + bias + tanh, coalesced store.
// Ain8: fp8 rows [N][64] ushorts (128B/row). Wt: bf16 [n][k].
template <bool FP8OUT>
__global__ __launch_bounds__(256) void k_layer(
    const int* __restrict__ rowptr, const int2* __restrict__ ew,
    const ushort* __restrict__ Ain8, const ushort* __restrict__ Wt,
    const float* __restrict__ bias, void* __restrict__ out, int n) {
    __shared__ ushort atile[16 * 136];   // bf16 tile, row stride 136
    __shared__ float otile[16 * 132];
    const int wid = threadIdx.x >> 6;
    const int lane = threadIdx.x & 63;
    const int base = blockIdx.x * 16;
    const int4* ew4 = (const int4*)ew;

    // ---- gather phase: 4 nodes per wave; lane owns features 2*lane, 2*lane+1
#pragma unroll
    for (int j = 0; j < 4; ++j) {
        int node = base + wid * 4 + j;
        float ax = 0.f, ay = 0.f;
        if (node < n) {
            int beg = rowptr[node];
            int end = rowptr[node + 1];
            int e = beg;
            for (; e + 8 <= end; e += 8) {
                int4 p0 = ew4[(e >> 1) + 0];
                int4 p1 = ew4[(e >> 1) + 1];
                int4 p2 = ew4[(e >> 1) + 2];
                int4 p3 = ew4[(e >> 1) + 3];
                uint u0 = Ain8[(size_t)p0.x * 64 + lane];
                uint u1 = Ain8[(size_t)p0.z * 64 + lane];
                uint u2 = Ain8[(size_t)p1.x * 64 + lane];
                uint u3 = Ain8[(size_t)p1.z * 64 + lane];
                uint u4 = Ain8[(size_t)p2.x * 64 + lane];
                uint u5 = Ain8[(size_t)p2.z * 64 + lane];
                uint u6 = Ain8[(size_t)p3.x * 64 + lane];
                uint u7 = Ain8[(size_t)p3.z * 64 + lane];
                float w0 = __int_as_float(p0.y), w1 = __int_as_float(p0.w);
                float w2 = __int_as_float(p1.y), w3 = __int_as_float(p1.w);
                float w4 = __int_as_float(p2.y), w5 = __int_as_float(p2.w);
                float w6 = __int_as_float(p3.y), w7 = __int_as_float(p3.w);
                f32x2 d0 = __builtin_amdgcn_cvt_pk_f32_fp8(u0, false);
                f32x2 d1 = __builtin_amdgcn_cvt_pk_f32_fp8(u1, false);
                f32x2 d2 = __builtin_amdgcn_cvt_pk_f32_fp8(u2, false);
                f32x2 d3 = __builtin_amdgcn_cvt_pk_f32_fp8(u3, false);
                f32x2 d4 = __builtin_amdgcn_cvt_pk_f32_fp8(u4, false);
                f32x2 d5 = __builtin_amdgcn_cvt_pk_f32_fp8(u5, false);
                f32x2 d6 = __builtin_amdgcn_cvt_pk_f32_fp8(u6, false);
                f32x2 d7 = __builtin_amdgcn_cvt_pk_f32_fp8(u7, false);
                ax += w0 * d0.x + w1 * d1.x + w2 * d2.x + w3 * d3.x
                    + w4 * d4.x + w5 * d5.x + w6 * d6.x + w7 * d7.x;
                ay += w0 * d0.y + w1 * d1.y + w2 * d2.y + w3 * d3.y
                    + w4 * d4.y + w5 * d5.y + w6 * d6.y + w7 * d7.y;
            }
            if (e < end) {   // pad=4 => remainder exactly 0 or 4
                int4 p0 = ew4[(e >> 1) + 0];
                int4 p1 = ew4[(e >> 1) + 1];
                uint u0 = Ain8[(size_t)p0.x * 64 + lane];
                uint u1 = Ain8[(size_t)p0.z * 64 + lane];
                uint u2 = Ain8[(size_t)p1.x * 64 + lane];
                uint u3 = Ain8[(size_t)p1.z * 64 + lane];
                float w0 = __int_as_float(p0.y), w1 = __int_as_float(p0.w);
                float w2 = __int_as_float(p1.y), w3 = __int_as_float(p1.w);
                f32x2 d0 = __builtin_amdgcn_cvt_pk_f32_fp8(u0, false);
                f32x2 d1 = __builtin_amdgcn_cvt_pk_f32_fp8(u1, false);
                f32x2 d2 = __builtin_amdgcn_cvt_pk_f32_fp8(u2, false);
                f32x2 d3 = __builtin_amdgcn_cvt_pk_f32_fp8(u3, false);
                ax += w0 * d0.x + w1 * d1.x + w2 * d2.x + w3 * d3.x;
                ay += w0 * d0.y + w1 * d1.y + w2 * d2.y + w3 * d3.y;
            }
        }
        ((uint*)atile)[(wid * 4 + j) * 68 + lane] = f2bf(ax) | (f2bf(ay) << 16);
    }
    __syncthreads();

    // ---- MFMA phase: wave wid computes col tiles {2*wid, 2*wid+1} ----
    const int m = lane & 15, quad = lane >> 4;
    const ushort* arow = atile + m * 136 + quad * 8;
    bf16x8 afr[4];
#pragma unroll
    for (int kc = 0; kc < 4; ++kc) afr[kc] = *(const bf16x8*)(arow + kc * 32);

    f32x4 acc[2];
#pragma unroll
    for (int t2 = 0; t2 < 2; ++t2) {
        acc[t2] = (f32x4){0.f, 0.f, 0.f, 0.f};
        const int t = wid * 2 + t2;
        const ushort* wrow = Wt + (size_t)(t * 16 + m) * 128 + quad * 8;
#pragma unroll
        for (int kc = 0; kc < 4; ++kc) {
            bf16x8 b = *(const bf16x8*)(wrow + kc * 32);
            acc[t2] = __builtin_amdgcn_mfma_f32_16x16x32_bf16(afr[kc], b, acc[t2], 0, 0, 0);
        }
    }

    // ---- epilogue: bias + tanh -> otile (C/D: row=quad*4+r, col=t*16+m) ----
#pragma unroll
    for (int t2 = 0; t2 < 2; ++t2) {
        const int t = wid * 2 + t2;
        float bb = bias[t * 16 + m];
#pragma unroll
        for (int r = 0; r < 4; ++r)
            otile[(quad * 4 + r) * 132 + t * 16 + m] = tanhf(acc[t2][r] + bb);
    }
    __syncthreads();

    // ---- coalesced store: thread -> (row = tid>>4, seg = tid&15) ----
    const int row = threadIdx.x >> 4, seg = threadIdx.x & 15;
    if (base + row < n) {
        const float* src = &otile[row * 132 + seg * 8];
        if (FP8OUT) {
            uint q0 = __builtin_amdgcn_cvt_pk_fp8_f32(src[0], src[1], 0, false);
            q0 = __builtin_amdgcn_cvt_pk_fp8_f32(src[2], src[3], q0, true);
            uint q1 = __builtin_amdgcn_cvt_pk_fp8_f32(src[4], src[5], 0, false);
            q1 = __builtin_amdgcn_cvt_pk_fp8_f32(src[6], src[7], q1, true);
            ((uint2*)out)[(size_t)(base + row) * 16 + seg] = make_uint2(q0, q1);
        } else {
            float4* dst = (float4*)((float*)out + (size_t)(base + row) * 128 + seg * 8);
            dst[0] = *(const float4*)(src);
            dst[1] = *(const float4*)(src + 4);
        }
    }
}

extern "C" void kernel_launch(void* const* d_in, const int* in_sizes, int n_in,
                              void* d_out, int out_size, void* d_ws, size_t ws_size,
                              hipStream_t stream) {
    const float* x  = (const float*)d_in[0];
    const int*   ei = (const int*)d_in[1];   // [2, E] int32: src then dst
    const float* W1 = (const float*)d_in[2];
    const float* b1 = (const float*)d_in[3];
    const float* W2 = (const float*)d_in[4];
    const float* b2 = (const float*)d_in[5];
    const int N = in_sizes[0] / D;   // 50000
    const int E = in_sizes[1] / 2;   // 500000
    float* out = (float*)d_out;

    char* ws = (char*)d_ws;
    const size_t KB = 1024, MB = 1024 * KB;
    int*    cnt      = (int*)(ws + 0);             // 200KB
    int*    cur      = (int*)(ws + 256 * KB);      // 200KB
    float*  dis      = (float*)(ws + 512 * KB);    // 200KB
    int*    rowptr   = (int*)(ws + 768 * KB);      // 200KB+4
    int*    partials = (int*)(ws + 1000 * KB);     // 1KB
    int2*   ew       = (int2*)(ws + 1 * MB);       // 5.6MB used
    uint*   Xf8      = (uint*)(ws + 9 * MB);       // 6.4MB (fp8 rows)
    uint*   H1f8     = (uint*)(ws + 16 * MB);      // 6.4MB (fp8 rows)
    ushort* Wt1      = (ushort*)(ws + 23 * MB);    // 32KB
    ushort* Wt2      = (ushort*)(ws + 23 * MB + 64 * KB);

    const int n4 = N * D / 4;
    const int nb = (n4 + 255) / 256;              // 6250
    const int cb = (E + 255) / 256;               // 1954
    const int sb = (N + 255) / 256;               // 196
    const int lblocks = (N + 15) / 16;            // 3125

    hipMemsetAsync(cnt, 0, (size_t)N * sizeof(int), stream);
    k_pre<<<nb + 128 + cb, 256, 0, stream>>>(
        (const float4*)x, (float4*)(out + (size_t)N * D), Xf8,
        W1, W2, Wt1, Wt2, ei + E, cnt, n4, E, nb);
    k_scan1<<<sb, 256, 0, stream>>>(cnt, partials, N);
    k_scan3<<<sb, 256, 0, stream>>>(cnt, partials, rowptr, dis, cur, ew, N, sb);
    k_fill<<<cb, 256, 0, stream>>>(ei, rowptr, dis, cur, ew, E);

    k_layer<true><<<lblocks, 256, 0, stream>>>(rowptr, ew, (const ushort*)Xf8, Wt1,
                                               b1, (void*)H1f8, N);
    k_layer<false><<<lblocks, 256, 0, stream>>>(rowptr, ew, (const ushort*)H1f8, Wt2,
                                                b2, (void*)out, N);
}